// Round 2
// baseline (543.774 us; speedup 1.0000x reference)
//
#include <hip/hip_runtime.h>

#define HH 256
#define WW 512
#define NCIN 16
#define NCOUT 32
#define NB 4

// Pre-pass: x (B, Cin, H, W) -> xt (B, H, W, Cin). XCD-swizzled block remap so
// each XCD writes (and later reads) a contiguous row band that fits its L2.
__global__ __launch_bounds__(256) void transpose_x_kernel(const float* __restrict__ x,
                                                          float* __restrict__ xt) {
    const int lb = (blockIdx.x & 7) * 256 + (blockIdx.x >> 3);   // 2048 blocks, bijective
    const int t = lb * 256 + threadIdx.x;   // 0 .. B*H*W-1
    const int c = t & (WW - 1);
    const int r = (t >> 9) & (HH - 1);
    const int b = t >> 17;
    const float* xp = x + ((size_t)(b * NCIN) * HH + r) * WW + c;  // coalesced per ci
    float v[NCIN];
#pragma unroll
    for (int ci = 0; ci < NCIN; ++ci) v[ci] = xp[(size_t)ci * (HH * WW)];
    float4* op = reinterpret_cast<float4*>(xt) + (size_t)t * 4;
#pragma unroll
    for (int q = 0; q < 4; ++q)
        op[q] = make_float4(v[q * 4 + 0], v[q * 4 + 1], v[q * 4 + 2], v[q * 4 + 3]);
}

// Fused grid_sample + stride-3 3x3 conv, 4 pixels (2 cols x 2 rows) per thread.
// Weight LDS broadcast reads amortized 4x vs round-1 (LDS was the bottleneck).
__global__ __launch_bounds__(256, 2) void sphere_conv4_kernel(const float* __restrict__ xt,
                                                              const float* __restrict__ weight,
                                                              const float* __restrict__ bias,
                                                              const float* __restrict__ grid,
                                                              float* __restrict__ out) {
    __shared__ float wlds[NCIN * 9 * NCOUT];   // 18 KiB, [ci*9+k][co]
    const int tid = threadIdx.x;
    for (int e = tid; e < NCIN * 9 * NCOUT; e += 256) {
        const int co  = e & (NCOUT - 1);
        const int cik = e >> 5;
        wlds[e] = weight[co * (NCIN * 9) + cik];
    }
    __syncthreads();

    // 512 blocks; XCD j gets logical blocks [j*64, j*64+64) = one batch half (128 rows)
    const int lb = (blockIdx.x & 7) * 64 + (blockIdx.x >> 3);
    const int pixbase = lb << 10;                  // 1024 pixels: 2 rows x 512 cols
    const int b  = pixbase >> 17;
    const int r0 = (pixbase >> 9) & (HH - 1);
    const int c0 = tid * 2;

    float acc[4][NCOUT];                           // px = (row<<1)|col
#pragma unroll
    for (int px = 0; px < 4; ++px)
#pragma unroll
        for (int o = 0; o < NCOUT; ++o) acc[px][o] = 0.0f;

    const float2* g2  = reinterpret_cast<const float2*>(grid);
    const float4* xt4 = reinterpret_cast<const float4*>(xt);

#pragma unroll 1
    for (int k = 0; k < 9; ++k) {
        const int kr = k / 3, kc = k - kr * 3;
        float cw[4][4];
        int   off[4][4];
#pragma unroll
        for (int px = 0; px < 4; ++px) {
            const int r = r0 + (px >> 1);
            const int c = c0 + (px & 1);
            const float2 g = g2[(r * 3 + kr) * (WW * 3) + (c * 3 + kc)];
            const float ix = ((g.x + 1.0f) * 0.5f) * (float)(WW - 1);
            const float iy = ((g.y + 1.0f) * 0.5f) * (float)(HH - 1);
            const float x0f = floorf(ix), y0f = floorf(iy);
            const float fx = ix - x0f, fy = iy - y0f;
            const int x0 = (int)x0f, y0 = (int)y0f;
            const int x1 = x0 + 1, y1 = y0 + 1;
            float wx0 = 1.0f - fx, wx1 = fx, wy0 = 1.0f - fy, wy1 = fy;
            if (x0 < 0 || x0 > WW - 1) wx0 = 0.0f;
            if (x1 < 0 || x1 > WW - 1) wx1 = 0.0f;
            if (y0 < 0 || y0 > HH - 1) wy0 = 0.0f;
            if (y1 < 0 || y1 > HH - 1) wy1 = 0.0f;
            const int cx0 = min(max(x0, 0), WW - 1), cx1 = min(max(x1, 0), WW - 1);
            const int cy0 = min(max(y0, 0), HH - 1), cy1 = min(max(y1, 0), HH - 1);
            cw[px][0] = wx0 * wy0;
            cw[px][1] = wx1 * wy0;
            cw[px][2] = wx0 * wy1;
            cw[px][3] = wx1 * wy1;
            const int row0 = (b * HH + cy0) * WW, row1 = (b * HH + cy1) * WW;
            off[px][0] = (row0 + cx0) * 4;
            off[px][1] = (row0 + cx1) * 4;
            off[px][2] = (row1 + cx0) * 4;
            off[px][3] = (row1 + cx1) * 4;
        }
#pragma unroll
        for (int q = 0; q < 4; ++q) {
            float sv[4][4];
#pragma unroll
            for (int px = 0; px < 4; ++px) {
                const float4 a00 = xt4[off[px][0] + q];
                const float4 a01 = xt4[off[px][1] + q];
                const float4 a10 = xt4[off[px][2] + q];
                const float4 a11 = xt4[off[px][3] + q];
                sv[px][0] = cw[px][0] * a00.x + cw[px][1] * a01.x + cw[px][2] * a10.x + cw[px][3] * a11.x;
                sv[px][1] = cw[px][0] * a00.y + cw[px][1] * a01.y + cw[px][2] * a10.y + cw[px][3] * a11.y;
                sv[px][2] = cw[px][0] * a00.z + cw[px][1] * a01.z + cw[px][2] * a10.z + cw[px][3] * a11.z;
                sv[px][3] = cw[px][0] * a00.w + cw[px][1] * a01.w + cw[px][2] * a10.w + cw[px][3] * a11.w;
            }
#pragma unroll
            for (int j = 0; j < 4; ++j) {
                const float4* wl =
                    reinterpret_cast<const float4*>(&wlds[((q * 4 + j) * 9 + k) * NCOUT]);
#pragma unroll
                for (int ow = 0; ow < 8; ++ow) {
                    const float4 wv = wl[ow];
#pragma unroll
                    for (int px = 0; px < 4; ++px) {
                        acc[px][ow * 4 + 0] += wv.x * sv[px][j];
                        acc[px][ow * 4 + 1] += wv.y * sv[px][j];
                        acc[px][ow * 4 + 2] += wv.z * sv[px][j];
                        acc[px][ow * 4 + 3] += wv.w * sv[px][j];
                    }
                }
            }
        }
    }

#pragma unroll
    for (int o = 0; o < NCOUT; ++o) {
        const float bo = bias[o];
        float* op = out + (((b * NCOUT + o) * HH + r0) * WW + c0);
        *reinterpret_cast<float2*>(op)      = make_float2(acc[0][o] + bo, acc[1][o] + bo);
        *reinterpret_cast<float2*>(op + WW) = make_float2(acc[2][o] + bo, acc[3][o] + bo);
    }
}

// Fallback (no workspace): round-1 direct-gather kernel, one pixel per thread.
__global__ __launch_bounds__(256) void sphere_conv_fallback(const float* __restrict__ x,
                                                            const float* __restrict__ weight,
                                                            const float* __restrict__ bias,
                                                            const float* __restrict__ grid,
                                                            float* __restrict__ out) {
    __shared__ float wlds[NCIN * 9 * NCOUT];
    const int tid = threadIdx.x;
    for (int e = tid; e < NCIN * 9 * NCOUT; e += 256) {
        const int co  = e & (NCOUT - 1);
        const int cik = e >> 5;
        wlds[e] = weight[co * (NCIN * 9) + cik];
    }
    __syncthreads();

    const int p = blockIdx.x * 256 + tid;
    const int c = p & (WW - 1);
    const int r = (p >> 9) & (HH - 1);
    const int b = p >> 17;

    float acc[NCOUT];
#pragma unroll
    for (int o = 0; o < NCOUT; ++o) acc[o] = 0.0f;

    const float2* g2 = reinterpret_cast<const float2*>(grid);

#pragma unroll 1
    for (int k = 0; k < 9; ++k) {
        const int kr = k / 3, kc = k - kr * 3;
        const float2 g = g2[(r * 3 + kr) * (WW * 3) + (c * 3 + kc)];
        const float ix = ((g.x + 1.0f) * 0.5f) * (float)(WW - 1);
        const float iy = ((g.y + 1.0f) * 0.5f) * (float)(HH - 1);
        const float x0f = floorf(ix), y0f = floorf(iy);
        const float fx = ix - x0f, fy = iy - y0f;
        const int x0 = (int)x0f, y0 = (int)y0f;
        const int x1 = x0 + 1, y1 = y0 + 1;
        float wx0 = 1.0f - fx, wx1 = fx, wy0 = 1.0f - fy, wy1 = fy;
        if (x0 < 0 || x0 > WW - 1) wx0 = 0.0f;
        if (x1 < 0 || x1 > WW - 1) wx1 = 0.0f;
        if (y0 < 0 || y0 > HH - 1) wy0 = 0.0f;
        if (y1 < 0 || y1 > HH - 1) wy1 = 0.0f;
        const int cx0 = min(max(x0, 0), WW - 1), cx1 = min(max(x1, 0), WW - 1);
        const int cy0 = min(max(y0, 0), HH - 1), cy1 = min(max(y1, 0), HH - 1);
        const float w00 = wx0 * wy0, w01 = wx1 * wy0, w10 = wx0 * wy1, w11 = wx1 * wy1;

#pragma unroll 1
        for (int ci = 0; ci < NCIN; ++ci) {
            const float* xb = x + (size_t)((b * NCIN + ci) * HH) * WW;
            const float a00 = xb[cy0 * WW + cx0];
            const float a01 = xb[cy0 * WW + cx1];
            const float a10 = xb[cy1 * WW + cx0];
            const float a11 = xb[cy1 * WW + cx1];
            const float s = w00 * a00 + w01 * a01 + w10 * a10 + w11 * a11;
            const float4* wl = reinterpret_cast<const float4*>(&wlds[(ci * 9 + k) * NCOUT]);
#pragma unroll
            for (int o = 0; o < 8; ++o) {
                const float4 wv = wl[o];
                acc[o * 4 + 0] += wv.x * s;
                acc[o * 4 + 1] += wv.y * s;
                acc[o * 4 + 2] += wv.z * s;
                acc[o * 4 + 3] += wv.w * s;
            }
        }
    }

    const int obase = ((b * NCOUT) * HH + r) * WW + c;
#pragma unroll
    for (int o = 0; o < NCOUT; ++o) {
        out[obase + o * (HH * WW)] = acc[o] + bias[o];
    }
}

extern "C" void kernel_launch(void* const* d_in, const int* in_sizes, int n_in,
                              void* d_out, int out_size, void* d_ws, size_t ws_size,
                              hipStream_t stream) {
    const float* x    = (const float*)d_in[0];
    const float* w    = (const float*)d_in[1];
    const float* bias = (const float*)d_in[2];
    const float* grid = (const float*)d_in[3];
    float* out = (float*)d_out;

    const size_t xt_bytes = (size_t)NB * HH * WW * NCIN * sizeof(float);  // 32 MiB

    if (ws_size >= xt_bytes) {
        float* xt = (float*)d_ws;
        transpose_x_kernel<<<2048, 256, 0, stream>>>(x, xt);
        sphere_conv4_kernel<<<512, 256, 0, stream>>>(xt, w, bias, grid, out);
    } else {
        sphere_conv_fallback<<<2048, 256, 0, stream>>>(x, w, bias, grid, out);
    }
}

// Round 4
// 131.195 us; speedup vs baseline: 4.1448x; 4.1448x over previous
//
#include <hip/hip_runtime.h>

#define HH 256
#define WW 512
#define NCIN 16
#define NCOUT 32
#define NB 4
#define KP 168     // padded K stride in half elems (336 B rows, 16B-aligned)
#define NPIX 64    // pixels per block

typedef _Float16 half8 __attribute__((ext_vector_type(8)));
typedef float f32x4 __attribute__((ext_vector_type(4)));

// Pre-pass: x (B, Cin, H, W) -> xt (B, H, W, Cin), XCD-swizzled blocks.
__global__ __launch_bounds__(256) void transpose_x_kernel(const float* __restrict__ x,
                                                          float* __restrict__ xt) {
    const int lb = (blockIdx.x & 7) * 256 + (blockIdx.x >> 3);
    const int t = lb * 256 + threadIdx.x;
    const int c = t & (WW - 1);
    const int r = (t >> 9) & (HH - 1);
    const int b = t >> 17;
    const float* xp = x + ((size_t)(b * NCIN) * HH + r) * WW + c;
    float v[NCIN];
#pragma unroll
    for (int ci = 0; ci < NCIN; ++ci) v[ci] = xp[(size_t)ci * (HH * WW)];
    float4* op = reinterpret_cast<float4*>(xt) + (size_t)t * 4;
#pragma unroll
    for (int q = 0; q < 4; ++q)
        op[q] = make_float4(v[q * 4 + 0], v[q * 4 + 1], v[q * 4 + 2], v[q * 4 + 3]);
}

// Implicit-GEMM: sample S-tile (64 px x K=144) to LDS in fp16, W in LDS fp16,
// conv via mfma_f32_16x16x32_f16. Each wave: 16 pixels x 32 couts.
__global__ __launch_bounds__(256, 2) void sphere_mfma_kernel(const float* __restrict__ xt,
                                                             const float* __restrict__ weight,
                                                             const float* __restrict__ bias,
                                                             const float* __restrict__ grid,
                                                             float* __restrict__ out) {
    __shared__ _Float16 Wl[NCOUT * KP];   // [cout][kk], kk = tap*16+ci, zero-padded K
    __shared__ _Float16 Sl[NPIX * KP];    // [p][kk], pad kk=144..167 zeroed below
    const int tid = threadIdx.x;

    for (int e = tid; e < NCOUT * KP; e += 256) {
        const int co = e / KP, kk = e - co * KP;
        float v = 0.0f;
        if (kk < 144) {
            const int tap = kk >> 4, ci = kk & 15;
            v = weight[co * 144 + ci * 9 + tap];
        }
        Wl[e] = (_Float16)v;
    }
    // Zero Sl's K-pad: the last MFMA K-step reads kk=144..159 (g4=2,3).
    // Round-3 NaN root cause: this region was uninitialized LDS.
    for (int e = tid; e < NPIX * (KP - 144); e += 256) {
        const int p = e / (KP - 144), q = e - p * (KP - 144);
        Sl[p * KP + 144 + q] = (_Float16)0.0f;
    }

    const int lb = ((blockIdx.x & 7) << 10) + (blockIdx.x >> 3);  // 8192 blocks, bijective
    const int pixbase = lb * NPIX;                                 // 64 consecutive cols, one row
    const int b    = pixbase >> 17;
    const int rimg = (pixbase >> 9) & (HH - 1);
    const int c0   = pixbase & (WW - 1);

    // ---- build S: tasks (p = tid&63, tap = tid>>6 + 4*round) ----
    const float2* g2  = reinterpret_cast<const float2*>(grid);
    const float4* xt4 = reinterpret_cast<const float4*>(xt);
    const int p = tid & 63;
    const int c = c0 + p;

    for (int tap = (tid >> 6); tap < 9; tap += 4) {
        const int kr = tap / 3, kc = tap - kr * 3;
        const float2 g = g2[((rimg * 3 + kr) * (WW * 3)) + (c * 3 + kc)];
        const float ix = ((g.x + 1.0f) * 0.5f) * (float)(WW - 1);
        const float iy = ((g.y + 1.0f) * 0.5f) * (float)(HH - 1);
        const float x0f = floorf(ix), y0f = floorf(iy);
        const float fx = ix - x0f, fy = iy - y0f;
        const int x0 = (int)x0f, y0 = (int)y0f;
        const int x1 = x0 + 1, y1 = y0 + 1;
        float wx0 = 1.0f - fx, wx1 = fx, wy0 = 1.0f - fy, wy1 = fy;
        if (x0 < 0 || x0 > WW - 1) wx0 = 0.0f;
        if (x1 < 0 || x1 > WW - 1) wx1 = 0.0f;
        if (y0 < 0 || y0 > HH - 1) wy0 = 0.0f;
        if (y1 < 0 || y1 > HH - 1) wy1 = 0.0f;
        const int cx0 = min(max(x0, 0), WW - 1), cx1 = min(max(x1, 0), WW - 1);
        const int cy0 = min(max(y0, 0), HH - 1), cy1 = min(max(y1, 0), HH - 1);
        const float w00 = wx0 * wy0, w01 = wx1 * wy0, w10 = wx0 * wy1, w11 = wx1 * wy1;
        const int row0 = (b * HH + cy0) * WW, row1 = (b * HH + cy1) * WW;
        const int o00 = (row0 + cx0) * 4, o01 = (row0 + cx1) * 4;
        const int o10 = (row1 + cx0) * 4, o11 = (row1 + cx1) * 4;

        half8 pk0, pk1;
#pragma unroll
        for (int q = 0; q < 4; ++q) {
            const float4 a00 = xt4[o00 + q], a01 = xt4[o01 + q];
            const float4 a10 = xt4[o10 + q], a11 = xt4[o11 + q];
            float sv[4];
            sv[0] = w00 * a00.x + w01 * a01.x + w10 * a10.x + w11 * a11.x;
            sv[1] = w00 * a00.y + w01 * a01.y + w10 * a10.y + w11 * a11.y;
            sv[2] = w00 * a00.z + w01 * a01.z + w10 * a10.z + w11 * a11.z;
            sv[3] = w00 * a00.w + w01 * a01.w + w10 * a10.w + w11 * a11.w;
#pragma unroll
            for (int j = 0; j < 4; ++j) {
                const int idx = q * 4 + j;
                if (idx < 8) pk0[idx] = (_Float16)sv[j];
                else         pk1[idx - 8] = (_Float16)sv[j];
            }
        }
        *reinterpret_cast<half8*>(&Sl[p * KP + tap * 16])     = pk0;
        *reinterpret_cast<half8*>(&Sl[p * KP + tap * 16 + 8]) = pk1;
    }
    __syncthreads();

    // ---- MFMA: wave wv owns pixels [wv*16, wv*16+16), couts 0..31 ----
    const int lane = tid & 63, wv = tid >> 6;
    const int col = lane & 15, g4 = lane >> 4;
    f32x4 acc0 = {0.f, 0.f, 0.f, 0.f}, acc1 = {0.f, 0.f, 0.f, 0.f};
#pragma unroll
    for (int step = 0; step < 5; ++step) {
        const int kb = step * 32 + g4 * 8;
        const half8 bf = *reinterpret_cast<const half8*>(&Sl[(wv * 16 + col) * KP + kb]);
        const half8 a0 = *reinterpret_cast<const half8*>(&Wl[col * KP + kb]);
        const half8 a1 = *reinterpret_cast<const half8*>(&Wl[(16 + col) * KP + kb]);
        acc0 = __builtin_amdgcn_mfma_f32_16x16x32_f16(a0, bf, acc0, 0, 0, 0);
        acc1 = __builtin_amdgcn_mfma_f32_16x16x32_f16(a1, bf, acc1, 0, 0, 0);
    }

    // ---- epilogue: C col=lane&15 (pixel), row=(lane>>4)*4+reg (cout) ----
    const int pix = c0 + wv * 16 + col;
    float* ob = out + (((size_t)(b * NCOUT) * HH + rimg) * WW) + pix;
#pragma unroll
    for (int m = 0; m < 2; ++m) {
        const f32x4 a = m ? acc1 : acc0;
#pragma unroll
        for (int r = 0; r < 4; ++r) {
            const int co = m * 16 + g4 * 4 + r;
            ob[(size_t)co * (HH * WW)] = a[r] + bias[co];
        }
    }
}

// Fallback (no workspace): round-1 direct-gather kernel (verified, ~146us).
__global__ __launch_bounds__(256) void sphere_conv_fallback(const float* __restrict__ x,
                                                            const float* __restrict__ weight,
                                                            const float* __restrict__ bias,
                                                            const float* __restrict__ grid,
                                                            float* __restrict__ out) {
    __shared__ float wlds[NCIN * 9 * NCOUT];
    const int tid = threadIdx.x;
    for (int e = tid; e < NCIN * 9 * NCOUT; e += 256) {
        const int co  = e & (NCOUT - 1);
        const int cik = e >> 5;
        wlds[e] = weight[co * (NCIN * 9) + cik];
    }
    __syncthreads();

    const int pindex = blockIdx.x * 256 + tid;
    const int c = pindex & (WW - 1);
    const int r = (pindex >> 9) & (HH - 1);
    const int b = pindex >> 17;

    float acc[NCOUT];
#pragma unroll
    for (int o = 0; o < NCOUT; ++o) acc[o] = 0.0f;

    const float2* g2 = reinterpret_cast<const float2*>(grid);

#pragma unroll 1
    for (int k = 0; k < 9; ++k) {
        const int kr = k / 3, kc = k - kr * 3;
        const float2 g = g2[(r * 3 + kr) * (WW * 3) + (c * 3 + kc)];
        const float ix = ((g.x + 1.0f) * 0.5f) * (float)(WW - 1);
        const float iy = ((g.y + 1.0f) * 0.5f) * (float)(HH - 1);
        const float x0f = floorf(ix), y0f = floorf(iy);
        const float fx = ix - x0f, fy = iy - y0f;
        const int x0 = (int)x0f, y0 = (int)y0f;
        const int x1 = x0 + 1, y1 = y0 + 1;
        float wx0 = 1.0f - fx, wx1 = fx, wy0 = 1.0f - fy, wy1 = fy;
        if (x0 < 0 || x0 > WW - 1) wx0 = 0.0f;
        if (x1 < 0 || x1 > WW - 1) wx1 = 0.0f;
        if (y0 < 0 || y0 > HH - 1) wy0 = 0.0f;
        if (y1 < 0 || y1 > HH - 1) wy1 = 0.0f;
        const int cx0 = min(max(x0, 0), WW - 1), cx1 = min(max(x1, 0), WW - 1);
        const int cy0 = min(max(y0, 0), HH - 1), cy1 = min(max(y1, 0), HH - 1);
        const float w00 = wx0 * wy0, w01 = wx1 * wy0, w10 = wx0 * wy1, w11 = wx1 * wy1;

#pragma unroll 1
        for (int ci = 0; ci < NCIN; ++ci) {
            const float* xb = x + (size_t)((b * NCIN + ci) * HH) * WW;
            const float a00 = xb[cy0 * WW + cx0];
            const float a01 = xb[cy0 * WW + cx1];
            const float a10 = xb[cy1 * WW + cx0];
            const float a11 = xb[cy1 * WW + cx1];
            const float s = w00 * a00 + w01 * a01 + w10 * a10 + w11 * a11;
            const float4* wl = reinterpret_cast<const float4*>(&wlds[(ci * 9 + k) * NCOUT]);
#pragma unroll
            for (int o = 0; o < 8; ++o) {
                const float4 wv = wl[o];
                acc[o * 4 + 0] += wv.x * s;
                acc[o * 4 + 1] += wv.y * s;
                acc[o * 4 + 2] += wv.z * s;
                acc[o * 4 + 3] += wv.w * s;
            }
        }
    }

    const int obase = ((b * NCOUT) * HH + r) * WW + c;
#pragma unroll
    for (int o = 0; o < NCOUT; ++o) {
        out[obase + o * (HH * WW)] = acc[o] + bias[o];
    }
}

extern "C" void kernel_launch(void* const* d_in, const int* in_sizes, int n_in,
                              void* d_out, int out_size, void* d_ws, size_t ws_size,
                              hipStream_t stream) {
    const float* x    = (const float*)d_in[0];
    const float* w    = (const float*)d_in[1];
    const float* bias = (const float*)d_in[2];
    const float* grid = (const float*)d_in[3];
    float* out = (float*)d_out;

    const size_t xt_bytes = (size_t)NB * HH * WW * NCIN * sizeof(float);  // 32 MiB

    if (ws_size >= xt_bytes) {
        float* xt = (float*)d_ws;
        transpose_x_kernel<<<2048, 256, 0, stream>>>(x, xt);
        sphere_mfma_kernel<<<8192, 256, 0, stream>>>(xt, w, bias, grid, out);
    } else {
        sphere_conv_fallback<<<2048, 256, 0, stream>>>(x, w, bias, grid, out);
    }
}

// Round 5
// 116.243 us; speedup vs baseline: 4.6779x; 1.1286x over previous
//
#include <hip/hip_runtime.h>

#define HH 256
#define WW 512
#define NCIN 16
#define NCOUT 32
#define NB 4
#define KP 168     // padded K stride in half elems (336 B rows; 336B stride = 2-way banks, free)
#define NPIX 64    // pixels per block

typedef _Float16 half4 __attribute__((ext_vector_type(4)));
typedef _Float16 half8 __attribute__((ext_vector_type(8)));
typedef float f32x4 __attribute__((ext_vector_type(4)));

// Pre-pass: x (B, Cin, H, W) -> xt (B, H, W, Cin), XCD-swizzled blocks.
__global__ __launch_bounds__(256) void transpose_x_kernel(const float* __restrict__ x,
                                                          float* __restrict__ xt) {
    const int lb = (blockIdx.x & 7) * 256 + (blockIdx.x >> 3);
    const int t = lb * 256 + threadIdx.x;
    const int c = t & (WW - 1);
    const int r = (t >> 9) & (HH - 1);
    const int b = t >> 17;
    const float* xp = x + ((size_t)(b * NCIN) * HH + r) * WW + c;
    float v[NCIN];
#pragma unroll
    for (int ci = 0; ci < NCIN; ++ci) v[ci] = xp[(size_t)ci * (HH * WW)];
    float4* op = reinterpret_cast<float4*>(xt) + (size_t)t * 4;
#pragma unroll
    for (int q = 0; q < 4; ++q)
        op[q] = make_float4(v[q * 4 + 0], v[q * 4 + 1], v[q * 4 + 2], v[q * 4 + 3]);
}

// Implicit-GEMM: sample S-tile (64 px x K=144) to LDS fp16, conv via MFMA.
// S-build is q-grouped: lane = pl*4 + q, so one corner gather instruction
// reads 16 pixels x 16B = 16 cachelines at 4 lanes/line (round-4 was 64
// lines/inst -> TA-throughput-bound at ~124us).
__global__ __launch_bounds__(256, 2) void sphere_mfma_kernel(const float* __restrict__ xt,
                                                             const float* __restrict__ weight,
                                                             const float* __restrict__ bias,
                                                             const float* __restrict__ grid,
                                                             float* __restrict__ out) {
    __shared__ _Float16 Wl[NCOUT * KP];   // [cout][kk], kk = tap*16+ci, zero-padded K
    __shared__ _Float16 Sl[NPIX * KP];    // [p][kk], pad kk=144..167 zeroed below
    const int tid = threadIdx.x;

    for (int e = tid; e < NCOUT * KP; e += 256) {
        const int co = e / KP, kk = e - co * KP;
        float v = 0.0f;
        if (kk < 144) {
            const int tap = kk >> 4, ci = kk & 15;
            v = weight[co * 144 + ci * 9 + tap];
        }
        Wl[e] = (_Float16)v;
    }
    // Zero Sl's K-pad (last MFMA K-step reads kk=144..159).
    for (int e = tid; e < NPIX * (KP - 144); e += 256) {
        const int p = e / (KP - 144), q = e - p * (KP - 144);
        Sl[p * KP + 144 + q] = (_Float16)0.0f;
    }

    const int lb = ((blockIdx.x & 7) << 10) + (blockIdx.x >> 3);  // 8192 blocks, bijective
    const int pixbase = lb * NPIX;                                 // 64 consecutive cols, one row
    const int b    = pixbase >> 17;
    const int rimg = (pixbase >> 9) & (HH - 1);
    const int c0   = pixbase & (WW - 1);

    const float2* g2  = reinterpret_cast<const float2*>(grid);
    const float4* xt4 = reinterpret_cast<const float4*>(xt);

    // ---- build S, q-grouped: wave wv owns pixels [wv*16, wv*16+16) ----
    const int lane = tid & 63, wv = tid >> 6;
    const int pl = lane >> 2;          // pixel within wave group
    const int q  = lane & 3;           // channel quad
    const int p  = wv * 16 + pl;       // pixel within block
    const int c  = c0 + p;

#pragma unroll 3
    for (int tap = 0; tap < 9; ++tap) {
        const int kr = tap / 3, kc = tap - kr * 3;
        const float2 g = g2[((rimg * 3 + kr) * (WW * 3)) + (c * 3 + kc)];
        const float ix = ((g.x + 1.0f) * 0.5f) * (float)(WW - 1);
        const float iy = ((g.y + 1.0f) * 0.5f) * (float)(HH - 1);
        const float x0f = floorf(ix), y0f = floorf(iy);
        const float fx = ix - x0f, fy = iy - y0f;
        const int x0 = (int)x0f, y0 = (int)y0f;
        const int x1 = x0 + 1, y1 = y0 + 1;
        float wx0 = 1.0f - fx, wx1 = fx, wy0 = 1.0f - fy, wy1 = fy;
        if (x0 < 0 || x0 > WW - 1) wx0 = 0.0f;
        if (x1 < 0 || x1 > WW - 1) wx1 = 0.0f;
        if (y0 < 0 || y0 > HH - 1) wy0 = 0.0f;
        if (y1 < 0 || y1 > HH - 1) wy1 = 0.0f;
        const int cx0 = min(max(x0, 0), WW - 1), cx1 = min(max(x1, 0), WW - 1);
        const int cy0 = min(max(y0, 0), HH - 1), cy1 = min(max(y1, 0), HH - 1);
        const float w00 = wx0 * wy0, w01 = wx1 * wy0, w10 = wx0 * wy1, w11 = wx1 * wy1;
        const int row0 = (b * HH + cy0) * WW, row1 = (b * HH + cy1) * WW;

        const float4 a00 = xt4[(row0 + cx0) * 4 + q];
        const float4 a01 = xt4[(row0 + cx1) * 4 + q];
        const float4 a10 = xt4[(row1 + cx0) * 4 + q];
        const float4 a11 = xt4[(row1 + cx1) * 4 + q];
        float sv[4];
        sv[0] = w00 * a00.x + w01 * a01.x + w10 * a10.x + w11 * a11.x;
        sv[1] = w00 * a00.y + w01 * a01.y + w10 * a10.y + w11 * a11.y;
        sv[2] = w00 * a00.z + w01 * a01.z + w10 * a10.z + w11 * a11.z;
        sv[3] = w00 * a00.w + w01 * a01.w + w10 * a10.w + w11 * a11.w;
        half4 pk;
#pragma unroll
        for (int j = 0; j < 4; ++j) pk[j] = (_Float16)sv[j];
        *reinterpret_cast<half4*>(&Sl[p * KP + tap * 16 + q * 4]) = pk;
    }
    __syncthreads();

    // ---- MFMA: wave wv owns pixels [wv*16, wv*16+16), couts 0..31 ----
    const int col = lane & 15, g4 = lane >> 4;
    f32x4 acc0 = {0.f, 0.f, 0.f, 0.f}, acc1 = {0.f, 0.f, 0.f, 0.f};
#pragma unroll
    for (int step = 0; step < 5; ++step) {
        const int kb = step * 32 + g4 * 8;
        const half8 bf = *reinterpret_cast<const half8*>(&Sl[(wv * 16 + col) * KP + kb]);
        const half8 a0 = *reinterpret_cast<const half8*>(&Wl[col * KP + kb]);
        const half8 a1 = *reinterpret_cast<const half8*>(&Wl[(16 + col) * KP + kb]);
        acc0 = __builtin_amdgcn_mfma_f32_16x16x32_f16(a0, bf, acc0, 0, 0, 0);
        acc1 = __builtin_amdgcn_mfma_f32_16x16x32_f16(a1, bf, acc1, 0, 0, 0);
    }

    // ---- epilogue: C col=lane&15 (pixel), row=(lane>>4)*4+reg (cout) ----
    const int pix = c0 + wv * 16 + col;
    float* ob = out + (((size_t)(b * NCOUT) * HH + rimg) * WW) + pix;
#pragma unroll
    for (int m = 0; m < 2; ++m) {
        const f32x4 a = m ? acc1 : acc0;
#pragma unroll
        for (int r = 0; r < 4; ++r) {
            const int co = m * 16 + g4 * 4 + r;
            ob[(size_t)co * (HH * WW)] = a[r] + bias[co];
        }
    }
}

// Fallback (no workspace): round-1 direct-gather kernel (verified, ~146us).
__global__ __launch_bounds__(256) void sphere_conv_fallback(const float* __restrict__ x,
                                                            const float* __restrict__ weight,
                                                            const float* __restrict__ bias,
                                                            const float* __restrict__ grid,
                                                            float* __restrict__ out) {
    __shared__ float wlds[NCIN * 9 * NCOUT];
    const int tid = threadIdx.x;
    for (int e = tid; e < NCIN * 9 * NCOUT; e += 256) {
        const int co  = e & (NCOUT - 1);
        const int cik = e >> 5;
        wlds[e] = weight[co * (NCIN * 9) + cik];
    }
    __syncthreads();

    const int pindex = blockIdx.x * 256 + tid;
    const int c = pindex & (WW - 1);
    const int r = (pindex >> 9) & (HH - 1);
    const int b = pindex >> 17;

    float acc[NCOUT];
#pragma unroll
    for (int o = 0; o < NCOUT; ++o) acc[o] = 0.0f;

    const float2* g2 = reinterpret_cast<const float2*>(grid);

#pragma unroll 1
    for (int k = 0; k < 9; ++k) {
        const int kr = k / 3, kc = k - kr * 3;
        const float2 g = g2[(r * 3 + kr) * (WW * 3) + (c * 3 + kc)];
        const float ix = ((g.x + 1.0f) * 0.5f) * (float)(WW - 1);
        const float iy = ((g.y + 1.0f) * 0.5f) * (float)(HH - 1);
        const float x0f = floorf(ix), y0f = floorf(iy);
        const float fx = ix - x0f, fy = iy - y0f;
        const int x0 = (int)x0f, y0 = (int)y0f;
        const int x1 = x0 + 1, y1 = y0 + 1;
        float wx0 = 1.0f - fx, wx1 = fx, wy0 = 1.0f - fy, wy1 = fy;
        if (x0 < 0 || x0 > WW - 1) wx0 = 0.0f;
        if (x1 < 0 || x1 > WW - 1) wx1 = 0.0f;
        if (y0 < 0 || y0 > HH - 1) wy0 = 0.0f;
        if (y1 < 0 || y1 > HH - 1) wy1 = 0.0f;
        const int cx0 = min(max(x0, 0), WW - 1), cx1 = min(max(x1, 0), WW - 1);
        const int cy0 = min(max(y0, 0), HH - 1), cy1 = min(max(y1, 0), HH - 1);
        const float w00 = wx0 * wy0, w01 = wx1 * wy0, w10 = wx0 * wy1, w11 = wx1 * wy1;

#pragma unroll 1
        for (int ci = 0; ci < NCIN; ++ci) {
            const float* xb = x + (size_t)((b * NCIN + ci) * HH) * WW;
            const float a00 = xb[cy0 * WW + cx0];
            const float a01 = xb[cy0 * WW + cx1];
            const float a10 = xb[cy1 * WW + cx0];
            const float a11 = xb[cy1 * WW + cx1];
            const float s = w00 * a00 + w01 * a01 + w10 * a10 + w11 * a11;
            const float4* wl = reinterpret_cast<const float4*>(&wlds[(ci * 9 + k) * NCOUT]);
#pragma unroll
            for (int o = 0; o < 8; ++o) {
                const float4 wv = wl[o];
                acc[o * 4 + 0] += wv.x * s;
                acc[o * 4 + 1] += wv.y * s;
                acc[o * 4 + 2] += wv.z * s;
                acc[o * 4 + 3] += wv.w * s;
            }
        }
    }

    const int obase = ((b * NCOUT) * HH + r) * WW + c;
#pragma unroll
    for (int o = 0; o < NCOUT; ++o) {
        out[obase + o * (HH * WW)] = acc[o] + bias[o];
    }
}

extern "C" void kernel_launch(void* const* d_in, const int* in_sizes, int n_in,
                              void* d_out, int out_size, void* d_ws, size_t ws_size,
                              hipStream_t stream) {
    const float* x    = (const float*)d_in[0];
    const float* w    = (const float*)d_in[1];
    const float* bias = (const float*)d_in[2];
    const float* grid = (const float*)d_in[3];
    float* out = (float*)d_out;

    const size_t xt_bytes = (size_t)NB * HH * WW * NCIN * sizeof(float);  // 32 MiB

    if (ws_size >= xt_bytes) {
        float* xt = (float*)d_ws;
        transpose_x_kernel<<<2048, 256, 0, stream>>>(x, xt);
        sphere_mfma_kernel<<<8192, 256, 0, stream>>>(xt, w, bias, grid, out);
    } else {
        sphere_conv_fallback<<<2048, 256, 0, stream>>>(x, w, bias, grid, out);
    }
}

// Round 6
// 115.304 us; speedup vs baseline: 4.7160x; 1.0081x over previous
//
#include <hip/hip_runtime.h>

#define HH 256
#define WW 512
#define NCIN 16
#define NCOUT 32
#define NB 4
#define KP 168     // padded K stride in half elems (336 B rows)
#define NPIX 64    // pixels per block

typedef _Float16 half4 __attribute__((ext_vector_type(4)));
typedef _Float16 half8 __attribute__((ext_vector_type(8)));
typedef float f32x4 __attribute__((ext_vector_type(4)));

// Pre-pass: x (B, Cin, H, W) -> xt (B, H, W, Cin), XCD-swizzled blocks.
__global__ __launch_bounds__(256) void transpose_x_kernel(const float* __restrict__ x,
                                                          float* __restrict__ xt) {
    const int lb = (blockIdx.x & 7) * 256 + (blockIdx.x >> 3);
    const int t = lb * 256 + threadIdx.x;
    const int c = t & (WW - 1);
    const int r = (t >> 9) & (HH - 1);
    const int b = t >> 17;
    const float* xp = x + ((size_t)(b * NCIN) * HH + r) * WW + c;
    float v[NCIN];
#pragma unroll
    for (int ci = 0; ci < NCIN; ++ci) v[ci] = xp[(size_t)ci * (HH * WW)];
    float4* op = reinterpret_cast<float4*>(xt) + (size_t)t * 4;
#pragma unroll
    for (int q = 0; q < 4; ++q)
        op[q] = make_float4(v[q * 4 + 0], v[q * 4 + 1], v[q * 4 + 2], v[q * 4 + 3]);
}

// Implicit-GEMM: sample S-tile (64 px x K=144) to LDS fp16, conv via MFMA.
// y-side interp quantities are column-independent (grid construction broadcasts
// new_r over w) -> computed ONCE per (row,tap) into a 9-entry LDS table.
// x is always in-bounds after the reference's mod-W wrap -> no x bounds code.
__global__ __launch_bounds__(256, 2) void sphere_mfma_kernel(const float* __restrict__ xt,
                                                             const float* __restrict__ weight,
                                                             const float* __restrict__ bias,
                                                             const float* __restrict__ grid,
                                                             float* __restrict__ out) {
    __shared__ _Float16 Wl[NCOUT * KP];   // [cout][kk], kk = tap*16+ci, zero-padded K
    __shared__ _Float16 Sl[NPIX * KP];    // [p][kk], pad kk=144..167 zeroed below
    __shared__ float4 tab[9];             // {wy0', wy1', bitcast(R0), bitcast(R1)}
    const int tid = threadIdx.x;

    for (int e = tid; e < NCOUT * KP; e += 256) {
        const int co = e / KP, kk = e - co * KP;
        float v = 0.0f;
        if (kk < 144) {
            const int tap = kk >> 4, ci = kk & 15;
            v = weight[co * 144 + ci * 9 + tap];
        }
        Wl[e] = (_Float16)v;
    }
    // Zero Sl's K-pad (last MFMA K-step reads kk=144..159).
    for (int e = tid; e < NPIX * (KP - 144); e += 256) {
        const int p = e / (KP - 144), q = e - p * (KP - 144);
        Sl[p * KP + 144 + q] = (_Float16)0.0f;
    }

    const int lb = ((blockIdx.x & 7) << 10) + (blockIdx.x >> 3);  // 8192 blocks, bijective
    const int pixbase = lb * NPIX;                                 // 64 consecutive cols, one row
    const int b    = pixbase >> 17;
    const int rimg = (pixbase >> 9) & (HH - 1);
    const int c0   = pixbase & (WW - 1);

    const float2* g2  = reinterpret_cast<const float2*>(grid);
    const float4* xt4 = reinterpret_cast<const float4*>(xt);

    // ---- phase A: per-tap y-side table (gy identical for all columns) ----
    if (tid < 9) {
        const int tap = tid;
        const int kr = tap / 3, kc = tap - kr * 3;
        const float2 g = g2[((rimg * 3 + kr) * (WW * 3)) + kc];   // column 0
        const float iy = ((g.y + 1.0f) * 0.5f) * (float)(HH - 1);
        const float y0f = floorf(iy);
        const float fy = iy - y0f;
        const int y0 = (int)y0f, y1 = y0 + 1;
        float wy0 = 1.0f - fy, wy1 = fy;
        if (y0 < 0 || y0 > HH - 1) wy0 = 0.0f;
        if (y1 < 0 || y1 > HH - 1) wy1 = 0.0f;
        const int cy0 = min(max(y0, 0), HH - 1), cy1 = min(max(y1, 0), HH - 1);
        const int R0 = ((b * HH + cy0) * WW) * 4;   // float4-index base of row cy0
        const int R1 = ((b * HH + cy1) * WW) * 4;
        tab[tap] = make_float4(wy0, wy1, __int_as_float(R0), __int_as_float(R1));
    }
    __syncthreads();

    // ---- phase B: build S, q-grouped (lane = pl*4 + q) ----
    const int lane = tid & 63, wv = tid >> 6;
    const int pl = lane >> 2;          // pixel within wave group
    const int q  = lane & 3;           // channel quad
    const int p  = wv * 16 + pl;       // pixel within block
    const int c  = c0 + p;

#pragma unroll 3
    for (int tap = 0; tap < 9; ++tap) {
        const int kr = tap / 3, kc = tap - kr * 3;
        const float4 t = tab[tap];
        const int R0 = __float_as_int(t.z), R1 = __float_as_int(t.w);
        const float gx = g2[((rimg * 3 + kr) * (WW * 3)) + (c * 3 + kc)].x;
        const float ix = ((gx + 1.0f) * 0.5f) * (float)(WW - 1);
        const float x0f = floorf(ix);
        const float fx = ix - x0f;
        const int x0 = (int)x0f;
        const float wx0 = 1.0f - fx;
        const float w00 = wx0 * t.x, w01 = fx * t.x, w10 = wx0 * t.y, w11 = fx * t.y;
        const int bq = (x0 << 2) + q;
        const int o00 = R0 + bq, o10 = R1 + bq;

        const float4 a00 = xt4[o00], a01 = xt4[o00 + 4];
        const float4 a10 = xt4[o10], a11 = xt4[o10 + 4];
        float sv[4];
        sv[0] = w00 * a00.x + w01 * a01.x + w10 * a10.x + w11 * a11.x;
        sv[1] = w00 * a00.y + w01 * a01.y + w10 * a10.y + w11 * a11.y;
        sv[2] = w00 * a00.z + w01 * a01.z + w10 * a10.z + w11 * a11.z;
        sv[3] = w00 * a00.w + w01 * a01.w + w10 * a10.w + w11 * a11.w;
        half4 pk;
#pragma unroll
        for (int j = 0; j < 4; ++j) pk[j] = (_Float16)sv[j];
        *reinterpret_cast<half4*>(&Sl[p * KP + tap * 16 + q * 4]) = pk;
    }
    __syncthreads();

    // ---- MFMA: wave wv owns pixels [wv*16, wv*16+16), couts 0..31 ----
    const int col = lane & 15, g4 = lane >> 4;
    f32x4 acc0 = {0.f, 0.f, 0.f, 0.f}, acc1 = {0.f, 0.f, 0.f, 0.f};
#pragma unroll
    for (int step = 0; step < 5; ++step) {
        const int kb = step * 32 + g4 * 8;
        const half8 bf = *reinterpret_cast<const half8*>(&Sl[(wv * 16 + col) * KP + kb]);
        const half8 a0 = *reinterpret_cast<const half8*>(&Wl[col * KP + kb]);
        const half8 a1 = *reinterpret_cast<const half8*>(&Wl[(16 + col) * KP + kb]);
        acc0 = __builtin_amdgcn_mfma_f32_16x16x32_f16(a0, bf, acc0, 0, 0, 0);
        acc1 = __builtin_amdgcn_mfma_f32_16x16x32_f16(a1, bf, acc1, 0, 0, 0);
    }

    // ---- epilogue: C col=lane&15 (pixel), row=(lane>>4)*4+reg (cout) ----
    const int pix = c0 + wv * 16 + col;
    float* ob = out + (((size_t)(b * NCOUT) * HH + rimg) * WW) + pix;
#pragma unroll
    for (int m = 0; m < 2; ++m) {
        const f32x4 a = m ? acc1 : acc0;
#pragma unroll
        for (int r = 0; r < 4; ++r) {
            const int co = m * 16 + g4 * 4 + r;
            ob[(size_t)co * (HH * WW)] = a[r] + bias[co];
        }
    }
}

// Fallback (no workspace): round-1 direct-gather kernel (verified, ~146us).
__global__ __launch_bounds__(256) void sphere_conv_fallback(const float* __restrict__ x,
                                                            const float* __restrict__ weight,
                                                            const float* __restrict__ bias,
                                                            const float* __restrict__ grid,
                                                            float* __restrict__ out) {
    __shared__ float wlds[NCIN * 9 * NCOUT];
    const int tid = threadIdx.x;
    for (int e = tid; e < NCIN * 9 * NCOUT; e += 256) {
        const int co  = e & (NCOUT - 1);
        const int cik = e >> 5;
        wlds[e] = weight[co * (NCIN * 9) + cik];
    }
    __syncthreads();

    const int pindex = blockIdx.x * 256 + tid;
    const int c = pindex & (WW - 1);
    const int r = (pindex >> 9) & (HH - 1);
    const int b = pindex >> 17;

    float acc[NCOUT];
#pragma unroll
    for (int o = 0; o < NCOUT; ++o) acc[o] = 0.0f;

    const float2* g2 = reinterpret_cast<const float2*>(grid);

#pragma unroll 1
    for (int k = 0; k < 9; ++k) {
        const int kr = k / 3, kc = k - kr * 3;
        const float2 g = g2[(r * 3 + kr) * (WW * 3) + (c * 3 + kc)];
        const float ix = ((g.x + 1.0f) * 0.5f) * (float)(WW - 1);
        const float iy = ((g.y + 1.0f) * 0.5f) * (float)(HH - 1);
        const float x0f = floorf(ix), y0f = floorf(iy);
        const float fx = ix - x0f, fy = iy - y0f;
        const int x0 = (int)x0f, y0 = (int)y0f;
        const int x1 = x0 + 1, y1 = y0 + 1;
        float wx0 = 1.0f - fx, wx1 = fx, wy0 = 1.0f - fy, wy1 = fy;
        if (x0 < 0 || x0 > WW - 1) wx0 = 0.0f;
        if (x1 < 0 || x1 > WW - 1) wx1 = 0.0f;
        if (y0 < 0 || y0 > HH - 1) wy0 = 0.0f;
        if (y1 < 0 || y1 > HH - 1) wy1 = 0.0f;
        const int cx0 = min(max(x0, 0), WW - 1), cx1 = min(max(x1, 0), WW - 1);
        const int cy0 = min(max(y0, 0), HH - 1), cy1 = min(max(y1, 0), HH - 1);
        const float w00 = wx0 * wy0, w01 = wx1 * wy0, w10 = wx0 * wy1, w11 = wx1 * wy1;

#pragma unroll 1
        for (int ci = 0; ci < NCIN; ++ci) {
            const float* xb = x + (size_t)((b * NCIN + ci) * HH) * WW;
            const float a00 = xb[cy0 * WW + cx0];
            const float a01 = xb[cy0 * WW + cx1];
            const float a10 = xb[cy1 * WW + cx0];
            const float a11 = xb[cy1 * WW + cx1];
            const float s = w00 * a00 + w01 * a01 + w10 * a10 + w11 * a11;
            const float4* wl = reinterpret_cast<const float4*>(&wlds[(ci * 9 + k) * NCOUT]);
#pragma unroll
            for (int o = 0; o < 8; ++o) {
                const float4 wv = wl[o];
                acc[o * 4 + 0] += wv.x * s;
                acc[o * 4 + 1] += wv.y * s;
                acc[o * 4 + 2] += wv.z * s;
                acc[o * 4 + 3] += wv.w * s;
            }
        }
    }

    const int obase = ((b * NCOUT) * HH + r) * WW + c;
#pragma unroll
    for (int o = 0; o < NCOUT; ++o) {
        out[obase + o * (HH * WW)] = acc[o] + bias[o];
    }
}

extern "C" void kernel_launch(void* const* d_in, const int* in_sizes, int n_in,
                              void* d_out, int out_size, void* d_ws, size_t ws_size,
                              hipStream_t stream) {
    const float* x    = (const float*)d_in[0];
    const float* w    = (const float*)d_in[1];
    const float* bias = (const float*)d_in[2];
    const float* grid = (const float*)d_in[3];
    float* out = (float*)d_out;

    const size_t xt_bytes = (size_t)NB * HH * WW * NCIN * sizeof(float);  // 32 MiB

    if (ws_size >= xt_bytes) {
        float* xt = (float*)d_ws;
        transpose_x_kernel<<<2048, 256, 0, stream>>>(x, xt);
        sphere_mfma_kernel<<<8192, 256, 0, stream>>>(xt, w, bias, grid, out);
    } else {
        sphere_conv_fallback<<<2048, 256, 0, stream>>>(x, w, bias, grid, out);
    }
}

// Round 8
// 84.182 us; speedup vs baseline: 6.4595x; 1.3697x over previous
//
#include <hip/hip_runtime.h>

#define HH 256
#define WW 512
#define NCIN 16
#define NCOUT 32
#define NB 4
#define KP 168     // Sl row stride in halfs (336 B)
#define WKP 168    // Wl row stride in halfs — MUST cover kk<160 read by last K-step (+zero pad)
#define NPIX 64    // pixels per block

typedef _Float16 half4 __attribute__((ext_vector_type(4)));
typedef _Float16 half8 __attribute__((ext_vector_type(8)));
typedef float f32x4 __attribute__((ext_vector_type(4)));

// Pre-pass: x (B, Cin, H, W) -> xt (B, H, W, Cin), XCD-swizzled blocks.
__global__ __launch_bounds__(256) void transpose_x_kernel(const float* __restrict__ x,
                                                          float* __restrict__ xt) {
    const int lb = (blockIdx.x & 7) * 256 + (blockIdx.x >> 3);
    const int t = lb * 256 + threadIdx.x;
    const int c = t & (WW - 1);
    const int r = (t >> 9) & (HH - 1);
    const int b = t >> 17;
    const float* xp = x + ((size_t)(b * NCIN) * HH + r) * WW + c;
    float v[NCIN];
#pragma unroll
    for (int ci = 0; ci < NCIN; ++ci) v[ci] = xp[(size_t)ci * (HH * WW)];
    float4* op = reinterpret_cast<float4*>(xt) + (size_t)t * 4;
#pragma unroll
    for (int q = 0; q < 4; ++q)
        op[q] = make_float4(v[q * 4 + 0], v[q * 4 + 1], v[q * 4 + 2], v[q * 4 + 3]);
}

// Implicit-GEMM: sample S-tile (64 px x K=144) to LDS fp16, conv via MFMA.
// Coalesced weight staging + LDS transpose; grid row slab staged to LDS.
// Round-8 fix: WKP back to 168 and Wl pad zeroed through kk=167 (the last
// MFMA K-step reads kk up to 159; round-7's WKP=152 read past the row/array).
__global__ __launch_bounds__(256, 2) void sphere_mfma_kernel(const float* __restrict__ xt,
                                                             const float* __restrict__ weight,
                                                             const float* __restrict__ bias,
                                                             const float* __restrict__ grid,
                                                             float* __restrict__ out) {
    __shared__ _Float16 Wl[NCOUT * WKP];  // [cout][kk], kk = tap*16+ci, zero-padded K
    __shared__ _Float16 Sl[NPIX * KP];    // [p][kk], pad kk=144..167 zeroed below
    __shared__ float2 Gl[3 * 192];        // grid slab: rows 3*rimg..+2, cols 3*c0..+191
    __shared__ float4 tab[9];             // {wy0', wy1', bitcast(R0), bitcast(R1)}
    const int tid = threadIdx.x;

    const int lb = ((blockIdx.x & 7) << 10) + (blockIdx.x >> 3);  // 8192 blocks, bijective
    const int pixbase = lb * NPIX;                                 // 64 consecutive cols, one row
    const int b    = pixbase >> 17;
    const int rimg = (pixbase >> 9) & (HH - 1);
    const int c0   = pixbase & (WW - 1);

    const float2* g2  = reinterpret_cast<const float2*>(grid);
    const float4* xt4 = reinterpret_cast<const float4*>(xt);

    // Zero Wl pad kk=144..167 (6 x half4 per row).
    for (int e = tid; e < NCOUT * 6; e += 256) {
        const int co = e / 6, j = e - co * 6;
        *reinterpret_cast<half4*>(&Wl[co * WKP + 144 + j * 4]) = half4{0, 0, 0, 0};
    }
    // Weight staging: coalesced global read (4 lines/inst), transposed ds_write_b16.
    for (int e = tid; e < NCOUT * NCIN * 9; e += 256) {
        const int co = e / 144, rem = e - co * 144;
        const int ci = rem / 9, tap = rem - ci * 9;
        Wl[co * WKP + tap * 16 + ci] = (_Float16)weight[e];
    }
    // Grid slab staging: 576 float2, fully coalesced.
    for (int e = tid; e < 576; e += 256) {
        const int kr = e / 192, j = e - kr * 192;
        Gl[e] = g2[(size_t)(rimg * 3 + kr) * (WW * 3) + c0 * 3 + j];
    }
    // Zero Sl's K-pad kk=144..167, vectorized.
    for (int e = tid; e < NPIX * 6; e += 256) {
        const int p = e / 6, j = e - p * 6;
        *reinterpret_cast<half4*>(&Sl[p * KP + 144 + j * 4]) = half4{0, 0, 0, 0};
    }
    // Phase A: per-tap y-side table (gy column-independent).
    if (tid < 9) {
        const int tap = tid;
        const int kr = tap / 3, kc = tap - kr * 3;
        const float2 g = g2[(size_t)(rimg * 3 + kr) * (WW * 3) + kc];   // column 0
        const float iy = ((g.y + 1.0f) * 0.5f) * (float)(HH - 1);
        const float y0f = floorf(iy);
        const float fy = iy - y0f;
        const int y0 = (int)y0f, y1 = y0 + 1;
        float wy0 = 1.0f - fy, wy1 = fy;
        if (y0 < 0 || y0 > HH - 1) wy0 = 0.0f;
        if (y1 < 0 || y1 > HH - 1) wy1 = 0.0f;
        const int cy0 = min(max(y0, 0), HH - 1), cy1 = min(max(y1, 0), HH - 1);
        const int R0 = ((b * HH + cy0) * WW) * 4;   // float4-index base of row cy0
        const int R1 = ((b * HH + cy1) * WW) * 4;
        tab[tap] = make_float4(wy0, wy1, __int_as_float(R0), __int_as_float(R1));
    }
    __syncthreads();

    // ---- phase B: build S, q-grouped (lane = pl*4 + q) ----
    const int lane = tid & 63, wv = tid >> 6;
    const int pl = lane >> 2;          // pixel within wave group
    const int q  = lane & 3;           // channel quad
    const int p  = wv * 16 + pl;       // pixel within block

#pragma unroll
    for (int tap = 0; tap < 9; ++tap) {
        const int kr = tap / 3, kc = tap - kr * 3;     // compile-time (full unroll)
        const float4 t = tab[tap];
        const int R0 = __float_as_int(t.z), R1 = __float_as_int(t.w);
        const float gx = Gl[kr * 192 + p * 3 + kc].x;  // broadcast across q, conflict-free
        const float ix = ((gx + 1.0f) * 0.5f) * (float)(WW - 1);
        const float x0f = floorf(ix);
        const float fx = ix - x0f;
        const int x0 = (int)x0f;
        const float wx0 = 1.0f - fx;
        const float w00 = wx0 * t.x, w01 = fx * t.x, w10 = wx0 * t.y, w11 = fx * t.y;
        const int bq = (x0 << 2) + q;
        const int o00 = R0 + bq, o10 = R1 + bq;

        const float4 a00 = xt4[o00], a01 = xt4[o00 + 4];
        const float4 a10 = xt4[o10], a11 = xt4[o10 + 4];
        float sv[4];
        sv[0] = w00 * a00.x + w01 * a01.x + w10 * a10.x + w11 * a11.x;
        sv[1] = w00 * a00.y + w01 * a01.y + w10 * a10.y + w11 * a11.y;
        sv[2] = w00 * a00.z + w01 * a01.z + w10 * a10.z + w11 * a11.z;
        sv[3] = w00 * a00.w + w01 * a01.w + w10 * a10.w + w11 * a11.w;
        half4 pk;
#pragma unroll
        for (int j = 0; j < 4; ++j) pk[j] = (_Float16)sv[j];
        *reinterpret_cast<half4*>(&Sl[p * KP + tap * 16 + q * 4]) = pk;
    }
    __syncthreads();

    // ---- MFMA: wave wv owns pixels [wv*16, wv*16+16), couts 0..31 ----
    const int col = lane & 15, g4 = lane >> 4;
    f32x4 acc0 = {0.f, 0.f, 0.f, 0.f}, acc1 = {0.f, 0.f, 0.f, 0.f};
#pragma unroll
    for (int step = 0; step < 5; ++step) {
        const int kb = step * 32 + g4 * 8;
        const half8 bf = *reinterpret_cast<const half8*>(&Sl[(wv * 16 + col) * KP + kb]);
        const half8 a0 = *reinterpret_cast<const half8*>(&Wl[col * WKP + kb]);
        const half8 a1 = *reinterpret_cast<const half8*>(&Wl[(16 + col) * WKP + kb]);
        acc0 = __builtin_amdgcn_mfma_f32_16x16x32_f16(a0, bf, acc0, 0, 0, 0);
        acc1 = __builtin_amdgcn_mfma_f32_16x16x32_f16(a1, bf, acc1, 0, 0, 0);
    }

    // ---- epilogue: C col=lane&15 (pixel), row=(lane>>4)*4+reg (cout) ----
    const int pix = c0 + wv * 16 + col;
    float* ob = out + (((size_t)(b * NCOUT) * HH + rimg) * WW) + pix;
#pragma unroll
    for (int m = 0; m < 2; ++m) {
        const f32x4 a = m ? acc1 : acc0;
#pragma unroll
        for (int r = 0; r < 4; ++r) {
            const int co = m * 16 + g4 * 4 + r;
            ob[(size_t)co * (HH * WW)] = a[r] + bias[co];
        }
    }
}

// Fallback (no workspace): round-1 direct-gather kernel (verified, ~146us).
__global__ __launch_bounds__(256) void sphere_conv_fallback(const float* __restrict__ x,
                                                            const float* __restrict__ weight,
                                                            const float* __restrict__ bias,
                                                            const float* __restrict__ grid,
                                                            float* __restrict__ out) {
    __shared__ float wlds[NCIN * 9 * NCOUT];
    const int tid = threadIdx.x;
    for (int e = tid; e < NCIN * 9 * NCOUT; e += 256) {
        const int co  = e & (NCOUT - 1);
        const int cik = e >> 5;
        wlds[e] = weight[co * (NCIN * 9) + cik];
    }
    __syncthreads();

    const int pindex = blockIdx.x * 256 + tid;
    const int c = pindex & (WW - 1);
    const int r = (pindex >> 9) & (HH - 1);
    const int b = pindex >> 17;

    float acc[NCOUT];
#pragma unroll
    for (int o = 0; o < NCOUT; ++o) acc[o] = 0.0f;

    const float2* g2 = reinterpret_cast<const float2*>(grid);

#pragma unroll 1
    for (int k = 0; k < 9; ++k) {
        const int kr = k / 3, kc = k - kr * 3;
        const float2 g = g2[(r * 3 + kr) * (WW * 3) + (c * 3 + kc)];
        const float ix = ((g.x + 1.0f) * 0.5f) * (float)(WW - 1);
        const float iy = ((g.y + 1.0f) * 0.5f) * (float)(HH - 1);
        const float x0f = floorf(ix), y0f = floorf(iy);
        const float fx = ix - x0f, fy = iy - y0f;
        const int x0 = (int)x0f, y0 = (int)y0f;
        const int x1 = x0 + 1, y1 = y0 + 1;
        float wx0 = 1.0f - fx, wx1 = fx, wy0 = 1.0f - fy, wy1 = fy;
        if (x0 < 0 || x0 > WW - 1) wx0 = 0.0f;
        if (x1 < 0 || x1 > WW - 1) wx1 = 0.0f;
        if (y0 < 0 || y0 > HH - 1) wy0 = 0.0f;
        if (y1 < 0 || y1 > HH - 1) wy1 = 0.0f;
        const int cx0 = min(max(x0, 0), WW - 1), cx1 = min(max(x1, 0), WW - 1);
        const int cy0 = min(max(y0, 0), HH - 1), cy1 = min(max(y1, 0), HH - 1);
        const float w00 = wx0 * wy0, w01 = wx1 * wy0, w10 = wx0 * wy1, w11 = wx1 * wy1;

#pragma unroll 1
        for (int ci = 0; ci < NCIN; ++ci) {
            const float* xb = x + (size_t)((b * NCIN + ci) * HH) * WW;
            const float a00 = xb[cy0 * WW + cx0];
            const float a01 = xb[cy0 * WW + cx1];
            const float a10 = xb[cy1 * WW + cx0];
            const float a11 = xb[cy1 * WW + cx1];
            const float s = w00 * a00 + w01 * a01 + w10 * a10 + w11 * a11;
            const float4* wl = reinterpret_cast<const float4*>(&wlds[(ci * 9 + k) * NCOUT]);
#pragma unroll
            for (int o = 0; o < 8; ++o) {
                const float4 wv = wl[o];
                acc[o * 4 + 0] += wv.x * s;
                acc[o * 4 + 1] += wv.y * s;
                acc[o * 4 + 2] += wv.z * s;
                acc[o * 4 + 3] += wv.w * s;
            }
        }
    }

    const int obase = ((b * NCOUT) * HH + r) * WW + c;
#pragma unroll
    for (int o = 0; o < NCOUT; ++o) {
        out[obase + o * (HH * WW)] = acc[o] + bias[o];
    }
}

extern "C" void kernel_launch(void* const* d_in, const int* in_sizes, int n_in,
                              void* d_out, int out_size, void* d_ws, size_t ws_size,
                              hipStream_t stream) {
    const float* x    = (const float*)d_in[0];
    const float* w    = (const float*)d_in[1];
    const float* bias = (const float*)d_in[2];
    const float* grid = (const float*)d_in[3];
    float* out = (float*)d_out;

    const size_t xt_bytes = (size_t)NB * HH * WW * NCIN * sizeof(float);  // 32 MiB

    if (ws_size >= xt_bytes) {
        float* xt = (float*)d_ws;
        transpose_x_kernel<<<2048, 256, 0, stream>>>(x, xt);
        sphere_mfma_kernel<<<8192, 256, 0, stream>>>(xt, w, bias, grid, out);
    } else {
        sphere_conv_fallback<<<2048, 256, 0, stream>>>(x, w, bias, grid, out);
    }
}